// Round 2
// baseline (3030.778 us; speedup 1.0000x reference)
//
#include <hip/hip_runtime.h>

// ---------------------------------------------------------------------------
// GCN: h1 = relu(Agg(x@W1)+b1); h2 = relu(Agg(h1@W2)+b2); out = mean(h2)@Wfc+bfc
// Agg_i = sum_{e: dst=i} h[src_e]*dinv[src]*dinv[dst] + h[i]*dinv[i]^2 (self loop)
// deg_i = 1 + in-degree(i); dinv = rsqrt(deg)
// NOTE: harness delivers integer inputs as int32 (edge_index is const int*).
// ---------------------------------------------------------------------------

__global__ __launch_bounds__(256) void k_init_deg(float* __restrict__ deg, int N) {
    int i = blockIdx.x * 256 + threadIdx.x;
    if (i < N) deg[i] = 1.0f;   // self-loop
}

__global__ __launch_bounds__(256) void k_deg_edges(const int* __restrict__ dst,
                                                   float* __restrict__ deg, int E) {
    int e = blockIdx.x * 256 + threadIdx.x;
    if (e < E) unsafeAtomicAdd(&deg[dst[e]], 1.0f);
}

__global__ __launch_bounds__(256) void k_rsqrt(float* __restrict__ deg, int N) {
    int i = blockIdx.x * 256 + threadIdx.x;
    if (i < N) deg[i] = rsqrtf(deg[i]);
}

// out[row][j] = sum_i f(in[row][i]) * W[i][j];  f = relu(v + bias) if relu_in
__global__ __launch_bounds__(256) void k_gemm64(const float* __restrict__ in,
                                                const float* __restrict__ W,
                                                const float* __restrict__ bias, int relu_in,
                                                float* __restrict__ out, int N) {
    __shared__ float Wl[64 * 64];
    for (int i = threadIdx.x; i < 64 * 64; i += 256) Wl[i] = W[i];
    __syncthreads();
    const int lane = threadIdx.x & 63;
    const int wave = threadIdx.x >> 6;
    const float bv = relu_in ? bias[lane] : 0.0f;
    for (int row = blockIdx.x * 4 + wave; row < N; row += gridDim.x * 4) {
        float x = in[(size_t)row * 64 + lane];
        if (relu_in) x = fmaxf(x + bv, 0.0f);
        float acc = 0.0f;
#pragma unroll
        for (int i = 0; i < 64; ++i)
            acc = fmaf(__shfl(x, i), Wl[i * 64 + lane], acc);
        out[(size_t)row * 64 + lane] = acc;
    }
}

// 16 threads per edge, float4 each: gather h[src]*norm, atomic scatter to out[dst]
__global__ __launch_bounds__(256) void k_edge_agg(const float* __restrict__ h,
                                                  const float* __restrict__ dinv,
                                                  const int* __restrict__ src,
                                                  const int* __restrict__ dst,
                                                  float* __restrict__ out, int E) {
    int t = blockIdx.x * 256 + threadIdx.x;
    int e = t >> 4;
    if (e >= E) return;
    int c = (t & 15) * 4;
    int s = src[e], d = dst[e];
    float nrm = dinv[s] * dinv[d];
    const float4 hv = *reinterpret_cast<const float4*>(h + (size_t)s * 64 + c);
    float* o = out + (size_t)d * 64 + c;
    unsafeAtomicAdd(o + 0, hv.x * nrm);
    unsafeAtomicAdd(o + 1, hv.y * nrm);
    unsafeAtomicAdd(o + 2, hv.z * nrm);
    unsafeAtomicAdd(o + 3, hv.w * nrm);
}

// out[i] += h[i] * dinv[i]^2  (self loop; separate dispatch => no atomics needed)
__global__ __launch_bounds__(256) void k_self_loop(const float* __restrict__ h,
                                                   const float* __restrict__ dinv,
                                                   float* __restrict__ out, int N) {
    int t = blockIdx.x * 256 + threadIdx.x;  // N*16 threads
    int i = t >> 4;
    if (i >= N) return;
    int c = (t & 15) * 4;
    float w = dinv[i]; w = w * w;
    const float4 hv = *reinterpret_cast<const float4*>(h + (size_t)i * 64 + c);
    float4* o = reinterpret_cast<float4*>(out + (size_t)i * 64 + c);
    float4 ov = *o;
    ov.x += hv.x * w; ov.y += hv.y * w; ov.z += hv.z * w; ov.w += hv.w * w;
    *o = ov;
}

// colsum[j] = sum_rows relu(in[row][j] + bias[j])
__global__ __launch_bounds__(256) void k_colsum(const float* __restrict__ in,
                                                const float* __restrict__ bias,
                                                float* __restrict__ colsum, int N) {
    const int lane = threadIdx.x & 63;
    const int wave = threadIdx.x >> 6;
    const float bv = bias[lane];
    float acc = 0.0f;
    for (int row = blockIdx.x * 4 + wave; row < N; row += gridDim.x * 4)
        acc += fmaxf(in[(size_t)row * 64 + lane] + bv, 0.0f);
    __shared__ float red[4][64];
    red[wave][lane] = acc;
    __syncthreads();
    if (wave == 0)
        unsafeAtomicAdd(&colsum[lane],
                        red[0][lane] + red[1][lane] + red[2][lane] + red[3][lane]);
}

// out[j] = (colsum/N) @ Wfc + bfc
__global__ void k_final(const float* __restrict__ colsum, const float* __restrict__ Wfc,
                        const float* __restrict__ bfc, float* __restrict__ out, float invN) {
    int j = threadIdx.x;  // 64 threads
    float acc = 0.0f;
#pragma unroll
    for (int i = 0; i < 64; ++i)
        acc = fmaf(colsum[i] * invN, Wfc[i * 64 + j], acc);
    out[j] = acc + bfc[j];
}

extern "C" void kernel_launch(void* const* d_in, const int* in_sizes, int n_in,
                              void* d_out, int out_size, void* d_ws, size_t ws_size,
                              hipStream_t stream) {
    const float* x   = (const float*)d_in[0];
    const int*   ei  = (const int*)d_in[1];     // int64 in reference -> int32 here
    const float* W1  = (const float*)d_in[2];
    const float* b1  = (const float*)d_in[3];
    const float* W2  = (const float*)d_in[4];
    const float* b2  = (const float*)d_in[5];
    const float* Wfc = (const float*)d_in[6];
    const float* bfc = (const float*)d_in[7];
    float*       out = (float*)d_out;

    const int N = in_sizes[0] / 64;
    const int E = in_sizes[1] / 2;
    const int* src = ei;       // edge_index[0]
    const int* dst = ei + E;   // edge_index[1]

    char* ws = (char*)d_ws;
    const size_t NB = (size_t)N * 64 * sizeof(float);          // 25.6 MB
    float* bufA = (float*)ws;                                  // h_pre
    float* bufB = (float*)(ws + NB);                           // agg
    float* dinv = (float*)(ws + 2 * NB);
    const size_t dinvB = ((size_t)N * sizeof(float) + 255) & ~(size_t)255;
    float* csum = (float*)(ws + 2 * NB + dinvB);

    const int blocksN   = (N + 255) / 256;
    const int blocksE   = (E + 255) / 256;
    const int blocksE16 = (int)(((long long)E * 16 + 255) / 256);
    const int blocksN16 = (int)(((long long)N * 16 + 255) / 256);

    // degrees -> dinv
    k_init_deg<<<blocksN, 256, 0, stream>>>(dinv, N);
    k_deg_edges<<<blocksE, 256, 0, stream>>>(dst, dinv, E);
    k_rsqrt<<<blocksN, 256, 0, stream>>>(dinv, N);

    // layer 1
    k_gemm64<<<1024, 256, 0, stream>>>(x, W1, nullptr, 0, bufA, N);
    hipMemsetAsync(bufB, 0, NB, stream);
    k_edge_agg<<<blocksE16, 256, 0, stream>>>(bufA, dinv, src, dst, bufB, E);
    k_self_loop<<<blocksN16, 256, 0, stream>>>(bufA, dinv, bufB, N);

    // layer 2 (fuse relu(agg1+b1) into GEMM input)
    k_gemm64<<<1024, 256, 0, stream>>>(bufB, W2, b1, 1, bufA, N);
    hipMemsetAsync(bufB, 0, NB, stream);
    k_edge_agg<<<blocksE16, 256, 0, stream>>>(bufA, dinv, src, dst, bufB, E);
    k_self_loop<<<blocksN16, 256, 0, stream>>>(bufA, dinv, bufB, N);

    // head: mean(h2) @ Wfc + bfc  (mean/GEMM commute by linearity)
    hipMemsetAsync(csum, 0, 64 * sizeof(float), stream);
    k_colsum<<<1024, 256, 0, stream>>>(bufB, b2, csum, N);
    k_final<<<1, 64, 0, stream>>>(csum, Wfc, bfc, out, 1.0f / (float)N);
}

// Round 3
// 532.439 us; speedup vs baseline: 5.6923x; 5.6923x over previous
//
#include <hip/hip_runtime.h>

// ---------------------------------------------------------------------------
// GCN via on-device CSR (gather-reduce, no f32 scatter atomics):
//   cnt[i]   = in-degree(i)                  (int histogram)
//   C[i]     = exclusive scan of cnt         (start positions)
//   scatter: esrc[pos] = src  (pos = atomicAdd(C[dst]))  -> C[i] becomes END pos
//   agg_i    = dinv[i] * ( dinv[i]*h[i] + sum_{k in rows(i)} dinv[esrc_k]*h[esrc_k] )
//   h1 = Agg(x@W1); h2 = Agg(relu(h1+b1)@W2); out = mean(relu(h2+b2))@Wfc+bfc
// edge_index arrives as int32 (harness converts integer inputs).
// ---------------------------------------------------------------------------

__global__ __launch_bounds__(256) void k_hist(const int* __restrict__ dst,
                                              unsigned* __restrict__ cnt, int E) {
    int e = blockIdx.x * 256 + threadIdx.x;
    if (e < E) atomicAdd(&cnt[dst[e]], 1u);
}

// per-256-block sums of cnt
__global__ __launch_bounds__(256) void k_blocksums(const unsigned* __restrict__ cnt,
                                                   unsigned* __restrict__ bsum, int N) {
    __shared__ unsigned s[256];
    int i = blockIdx.x * 256 + threadIdx.x;
    s[threadIdx.x] = (i < N) ? cnt[i] : 0u;
    __syncthreads();
    for (int off = 128; off > 0; off >>= 1) {
        if (threadIdx.x < off) s[threadIdx.x] += s[threadIdx.x + off];
        __syncthreads();
    }
    if (threadIdx.x == 0) bsum[blockIdx.x] = s[0];
}

// exclusive scan of bsum (nb <= 512), single block of 512
__global__ __launch_bounds__(512) void k_scan_bsum(unsigned* __restrict__ bsum, int nb) {
    __shared__ unsigned s[512];
    int t = threadIdx.x;
    unsigned v = (t < nb) ? bsum[t] : 0u;
    s[t] = v;
    __syncthreads();
    for (int off = 1; off < 512; off <<= 1) {
        unsigned a = (t >= off) ? s[t - off] : 0u;
        __syncthreads();
        s[t] += a;
        __syncthreads();
    }
    if (t < nb) bsum[t] = s[t] - v;   // exclusive
}

// C[i] = global exclusive scan; dinv[i] = rsqrt(1 + cnt[i])
__global__ __launch_bounds__(256) void k_scan_write(const unsigned* __restrict__ cnt,
                                                    const unsigned* __restrict__ bsum,
                                                    unsigned* __restrict__ C,
                                                    float* __restrict__ dinv, int N) {
    __shared__ unsigned s[256];
    int t = threadIdx.x;
    int i = blockIdx.x * 256 + t;
    unsigned c = (i < N) ? cnt[i] : 0u;
    s[t] = c;
    __syncthreads();
    for (int off = 1; off < 256; off <<= 1) {
        unsigned a = (t >= off) ? s[t - off] : 0u;
        __syncthreads();
        s[t] += a;
        __syncthreads();
    }
    if (i < N) {
        C[i] = bsum[blockIdx.x] + s[t] - c;       // exclusive start
        dinv[i] = rsqrtf(1.0f + (float)c);        // +1 self-loop
    }
}

// scatter edge sources; after this, C[i] == end position of node i's row
__global__ __launch_bounds__(256) void k_scatter(const int* __restrict__ src,
                                                 const int* __restrict__ dst,
                                                 unsigned* __restrict__ C,
                                                 int* __restrict__ esrc, int E) {
    int e = blockIdx.x * 256 + threadIdx.x;
    if (e >= E) return;
    unsigned pos = atomicAdd(&C[dst[e]], 1u);
    esrc[pos] = src[e];
}

// out[row][j] = sum_i f(in[row][i]) * W[i][j];  f = relu(v + bias) if relu_in
__global__ __launch_bounds__(256) void k_gemm64(const float* __restrict__ in,
                                                const float* __restrict__ W,
                                                const float* __restrict__ bias, int relu_in,
                                                float* __restrict__ out, int N) {
    __shared__ float Wl[64 * 64];
    for (int i = threadIdx.x; i < 64 * 64; i += 256) Wl[i] = W[i];
    __syncthreads();
    const int lane = threadIdx.x & 63;
    const int wave = threadIdx.x >> 6;
    const float bv = relu_in ? bias[lane] : 0.0f;
    for (int row = blockIdx.x * 4 + wave; row < N; row += gridDim.x * 4) {
        float x = in[(size_t)row * 64 + lane];
        if (relu_in) x = fmaxf(x + bv, 0.0f);
        float acc = 0.0f;
#pragma unroll
        for (int i = 0; i < 64; ++i)
            acc = fmaf(__shfl(x, i), Wl[i * 64 + lane], acc);
        out[(size_t)row * 64 + lane] = acc;
    }
}

// CSR gather-aggregate: 16 threads/node, float4 per thread. Self-loop fused.
__global__ __launch_bounds__(256) void k_agg_csr(const float* __restrict__ h,
                                                 const float* __restrict__ dinv,
                                                 const unsigned* __restrict__ Cend,
                                                 const int* __restrict__ esrc,
                                                 float* __restrict__ out, int N) {
    int g = blockIdx.x * 16 + (threadIdx.x >> 4);   // node
    if (g >= N) return;
    int c = (threadIdx.x & 15) * 4;
    unsigned start = (g == 0) ? 0u : Cend[g - 1];
    unsigned end = Cend[g];
    float di = dinv[g];
    float4 hv = *reinterpret_cast<const float4*>(h + (size_t)g * 64 + c);
    float4 sum;
    sum.x = di * hv.x; sum.y = di * hv.y; sum.z = di * hv.z; sum.w = di * hv.w;
    for (unsigned k = start; k < end; ++k) {
        int s = esrc[k];
        float dv = dinv[s];
        const float4 sv = *reinterpret_cast<const float4*>(h + (size_t)s * 64 + c);
        sum.x = fmaf(dv, sv.x, sum.x);
        sum.y = fmaf(dv, sv.y, sum.y);
        sum.z = fmaf(dv, sv.z, sum.z);
        sum.w = fmaf(dv, sv.w, sum.w);
    }
    float4 o;
    o.x = di * sum.x; o.y = di * sum.y; o.z = di * sum.z; o.w = di * sum.w;
    *reinterpret_cast<float4*>(out + (size_t)g * 64 + c) = o;
}

// colsum[j] = sum_rows relu(in[row][j] + bias[j])
__global__ __launch_bounds__(256) void k_colsum(const float* __restrict__ in,
                                                const float* __restrict__ bias,
                                                float* __restrict__ colsum, int N) {
    const int lane = threadIdx.x & 63;
    const int wave = threadIdx.x >> 6;
    const float bv = bias[lane];
    float acc = 0.0f;
    for (int row = blockIdx.x * 4 + wave; row < N; row += gridDim.x * 4)
        acc += fmaxf(in[(size_t)row * 64 + lane] + bv, 0.0f);
    __shared__ float red[4][64];
    red[wave][lane] = acc;
    __syncthreads();
    if (wave == 0)
        unsafeAtomicAdd(&colsum[lane],
                        red[0][lane] + red[1][lane] + red[2][lane] + red[3][lane]);
}

// out[j] = (colsum/N) @ Wfc + bfc
__global__ void k_final(const float* __restrict__ colsum, const float* __restrict__ Wfc,
                        const float* __restrict__ bfc, float* __restrict__ out, float invN) {
    int j = threadIdx.x;  // 64 threads
    float acc = 0.0f;
#pragma unroll
    for (int i = 0; i < 64; ++i)
        acc = fmaf(colsum[i] * invN, Wfc[i * 64 + j], acc);
    out[j] = acc + bfc[j];
}

extern "C" void kernel_launch(void* const* d_in, const int* in_sizes, int n_in,
                              void* d_out, int out_size, void* d_ws, size_t ws_size,
                              hipStream_t stream) {
    const float* x   = (const float*)d_in[0];
    const int*   ei  = (const int*)d_in[1];
    const float* W1  = (const float*)d_in[2];
    const float* b1  = (const float*)d_in[3];
    const float* W2  = (const float*)d_in[4];
    const float* b2  = (const float*)d_in[5];
    const float* Wfc = (const float*)d_in[6];
    const float* bfc = (const float*)d_in[7];
    float*       out = (float*)d_out;

    const int N = in_sizes[0] / 64;
    const int E = in_sizes[1] / 2;
    const int* src = ei;       // edge_index[0]
    const int* dst = ei + E;   // edge_index[1]

    char* ws = (char*)d_ws;
    const size_t NB  = (size_t)N * 64 * sizeof(float);               // 25.6 MB
    const size_t N4  = (((size_t)N * 4) + 255) & ~(size_t)255;       // padded N ints
    float*    bufA = (float*)ws;
    float*    bufB = (float*)(ws + NB);
    float*    dinv = (float*)(ws + 2 * NB);
    unsigned* cnt  = (unsigned*)(ws + 2 * NB + N4);
    unsigned* C    = (unsigned*)(ws + 2 * NB + 2 * N4);
    unsigned* bsum = (unsigned*)(ws + 2 * NB + 3 * N4);
    float*    csum = (float*)(ws + 2 * NB + 3 * N4 + 4096);
    int*      esrc = (int*)(ws + 2 * NB + 3 * N4 + 8192);            // E ints

    const int NBLK = (N + 255) / 256;     // 391
    const int EBLK = (E + 255) / 256;
    const int GBLK = (N + 15) / 16;       // agg blocks

    // ---- CSR build ----
    hipMemsetAsync(cnt, 0, (size_t)N * 4, stream);
    k_hist<<<EBLK, 256, 0, stream>>>(dst, cnt, E);
    k_blocksums<<<NBLK, 256, 0, stream>>>(cnt, bsum, N);
    k_scan_bsum<<<1, 512, 0, stream>>>(bsum, NBLK);
    k_scan_write<<<NBLK, 256, 0, stream>>>(cnt, bsum, C, dinv, N);
    k_scatter<<<EBLK, 256, 0, stream>>>(src, dst, C, esrc, E);

    // ---- layer 1 ----
    k_gemm64<<<1024, 256, 0, stream>>>(x, W1, nullptr, 0, bufA, N);
    k_agg_csr<<<GBLK, 256, 0, stream>>>(bufA, dinv, C, esrc, bufB, N);

    // ---- layer 2 (relu(agg1+b1) fused into GEMM input) ----
    k_gemm64<<<1024, 256, 0, stream>>>(bufB, W2, b1, 1, bufA, N);
    k_agg_csr<<<GBLK, 256, 0, stream>>>(bufA, dinv, C, esrc, bufB, N);

    // ---- head: mean(relu(h2+b2)) @ Wfc + bfc ----
    hipMemsetAsync(csum, 0, 64 * sizeof(float), stream);
    k_colsum<<<1024, 256, 0, stream>>>(bufB, b2, csum, N);
    k_final<<<1, 64, 0, stream>>>(csum, Wfc, bfc, out, 1.0f / (float)N);
}